// Round 2
// baseline (5915.332 us; speedup 1.0000x reference)
//
#include <hip/hip_runtime.h>
#include <hip/hip_bf16.h>
#include <math.h>

#define S   4096
#define L   16
#define DW  128
#define DC  64
#define HH  256
#define TT  50
#define KX  (DW + DC)   // 192
#define G4  (4 * HH)    // 1024
#define CWPG 8
#define SB  16

typedef unsigned long long u64;

__device__ __forceinline__ float frcp(float x) { return __builtin_amdgcn_rcpf(x); }
__device__ __forceinline__ float fsigmoid(float x) { return frcp(1.f + __expf(-x)); }
__device__ __forceinline__ float ftanh(float x) {
    float ax = fabsf(x);
    float t  = __expf(-2.f * ax);
    float r  = (1.f - t) * frcp(1.f + t);
    return x < 0.f ? -r : r;
}

// tag-embedded coherent publish/poll: no fences, no bulk L2 flush ever.
__device__ __forceinline__ void publish_h(u64* p, int tag, float v) {
    u64 pk = ((u64)(unsigned)tag << 32) | (u64)__float_as_uint(v);
    __hip_atomic_store(p, pk, __ATOMIC_RELAXED, __HIP_MEMORY_SCOPE_AGENT);
}
__device__ __forceinline__ float poll_h(const u64* p, int tag) {
    u64 v;
    do {
        v = __hip_atomic_load(p, __ATOMIC_RELAXED, __HIP_MEMORY_SCOPE_AGENT);
    } while ((int)(unsigned)(v >> 32) != tag);
    return __uint_as_float((unsigned)v);
}

// ---------------------------------------------------------------------------
// Kernel A: char-level LSTM. One workgroup (256 thr = 4 waves) handles CWPG
// words. Wave g = gate type (i,f,g,o), lane j = hidden element. Char weights
// register-cached per lane. x_t and h broadcast from LDS.
// ---------------------------------------------------------------------------
__global__ __launch_bounds__(256) void char_lstm_kernel(
    const int* __restrict__ char_ids, const int* __restrict__ word_len,
    const float* __restrict__ char_emb,
    const float* __restrict__ cWih, const float* __restrict__ cWhh,
    const float* __restrict__ cbih, const float* __restrict__ cbhh,
    float* __restrict__ h_char)
{
    const int t = threadIdx.x;
    const int g = t >> 6;     // gate type 0..3
    const int j = t & 63;     // hidden element
    const int r = g * 64 + j; // gate row

    float wih[64], whh[64];
#pragma unroll
    for (int k = 0; k < 64; ++k) wih[k] = cWih[r * 64 + k];
#pragma unroll
    for (int k = 0; k < 64; ++k) whh[k] = cWhh[r * 64 + k];
    const float cb = cbih[r] + cbhh[r];

    __shared__ float ce[L * 64];
    __shared__ float hbuf[64];
    __shared__ float gbuf[256];
    __shared__ int   ids[L];
    __shared__ int   wlen;

    const int w0 = blockIdx.x * CWPG;
    for (int wi = 0; wi < CWPG; ++wi) {
        const int w = w0 + wi;
        if (t < L)   ids[t] = char_ids[w * L + t];
        if (t == 64) wlen = word_len[w];
        if (t < 64)  hbuf[t] = 0.f;
        float c = 0.f;     // live in wave 0 lanes
        float hreg = 0.f;  // live in wave 0 lanes
        __syncthreads();
        for (int i = t; i < L * 64; i += 256)
            ce[i] = char_emb[ids[i >> 6] * 64 + (i & 63)];
        __syncthreads();

        for (int step = 0; step < L; ++step) {
            float acc = cb;
            const float* x = &ce[step * 64];
#pragma unroll
            for (int k = 0; k < 64; k += 4) {
                float4 xv = *(const float4*)&x[k];
                acc += wih[k] * xv.x + wih[k + 1] * xv.y + wih[k + 2] * xv.z + wih[k + 3] * xv.w;
            }
#pragma unroll
            for (int k = 0; k < 64; k += 4) {
                float4 hv = *(const float4*)&hbuf[k];
                acc += whh[k] * hv.x + whh[k + 1] * hv.y + whh[k + 2] * hv.z + whh[k + 3] * hv.w;
            }
            float a = (g == 2) ? ftanh(acc) : fsigmoid(acc);
            gbuf[r] = a;
            __syncthreads();
            if (g == 0) {
                if (step < wlen) {   // freeze state past word length
                    float iv = gbuf[j], fv = gbuf[64 + j], gg = gbuf[128 + j], ov = gbuf[192 + j];
                    c = fv * c + iv * gg;
                    hreg = ov * ftanh(c);
                }
                hbuf[j] = hreg;
            }
            __syncthreads();
        }
        if (g == 0) h_char[w * 64 + j] = hreg;
        __syncthreads();
    }
}

// ---------------------------------------------------------------------------
// Kernel T: transpose w_Wih [1024,192] -> Wt [192,1024] for coalesced GEMM.
// ---------------------------------------------------------------------------
__global__ void transpose_wih(const float* __restrict__ W, float* __restrict__ Wt)
{
    int idx = blockIdx.x * 256 + threadIdx.x;
    if (idx < KX * G4) {
        int r = idx & (G4 - 1);
        int k = idx >> 10;
        Wt[idx] = W[r * KX + k];
    }
}

// ---------------------------------------------------------------------------
// Kernel B: Xp[s][r] = (we[s] || h_char[s]) . w_Wih[r] + w_bih[r] + w_bhh[r]
// Block handles SB=16 sentence rows x all 1024 gate rows.
// ---------------------------------------------------------------------------
__global__ __launch_bounds__(256) void xproj_kernel(
    const int* __restrict__ word_ids, const float* __restrict__ word_emb,
    const float* __restrict__ h_char, const float* __restrict__ Wt,
    const float* __restrict__ wbih, const float* __restrict__ wbhh,
    float* __restrict__ Xp)
{
    const int t = threadIdx.x;
    const int s0 = blockIdx.x * SB;
    __shared__ float xs[SB][KX];
    __shared__ int   wid[SB];
    if (t < SB) wid[t] = word_ids[s0 + t];
    __syncthreads();
    for (int i = t; i < SB * DW; i += 256) {
        int s = i >> 7, k = i & 127;
        xs[s][k] = word_emb[wid[s] * DW + k];
    }
    for (int i = t; i < SB * DC; i += 256) {
        int s = i >> 6, k = i & 63;
        xs[s][DW + k] = h_char[(s0 + s) * DC + k];
    }
    __syncthreads();

    float acc[4][SB];
#pragma unroll
    for (int c = 0; c < 4; ++c)
#pragma unroll
        for (int s = 0; s < SB; ++s) acc[c][s] = 0.f;

    for (int kk = 0; kk < KX; ++kk) {
        float w0v = Wt[kk * G4 + t];
        float w1v = Wt[kk * G4 + 256 + t];
        float w2v = Wt[kk * G4 + 512 + t];
        float w3v = Wt[kk * G4 + 768 + t];
#pragma unroll
        for (int s = 0; s < SB; ++s) {
            float xv = xs[s][kk];
            acc[0][s] += w0v * xv;
            acc[1][s] += w1v * xv;
            acc[2][s] += w2v * xv;
            acc[3][s] += w3v * xv;
        }
    }
#pragma unroll
    for (int c = 0; c < 4; ++c) {
        int r = c * 256 + t;
        float bb = wbih[r] + wbhh[r];
#pragma unroll
        for (int s = 0; s < SB; ++s) Xp[(s0 + s) * G4 + r] = acc[c][s] + bb;
    }
}

// ---------------------------------------------------------------------------
// Kernel C: word-level LSTM recurrence, 4096 sequential steps.
// 4 blocks x 1024 threads. Block b owns h-slice [b*64, b*64+64): gate rows
// {gt*256 + b*64 + jj}. Thread = (row rl=t>>2, k-quarter q=t&3); Whh slice
// (64 fp32) in VGPRs. Cross-block h exchange via tag-embedded 64-bit relaxed
// agent atomics (no fences, no flag array, no bulk L2 ops).
// ---------------------------------------------------------------------------
__global__ __launch_bounds__(1024) void word_lstm_kernel(
    const float* __restrict__ Xp, const float* __restrict__ Whh,
    u64* __restrict__ hs64, float* __restrict__ hs)
{
    const int b  = blockIdx.x;   // 0..3
    const int t  = threadIdx.x;
    const int rl = t >> 2;       // 0..255 row-local
    const int q  = t & 3;        // k-quarter
    const int gt = rl >> 6;      // gate type
    const int jj = rl & 63;      // h element within slice
    const int r  = gt * 256 + b * 64 + jj;  // global gate row

    float w[64];
#pragma unroll
    for (int i = 0; i < 64; ++i)
        w[i] = Whh[r * 256 + q * 64 + i];

    float c = 0.f;  // state held by threads t<64

    __shared__ float h_lds[4 * 68];  // quarter q at offset 68*q: +68 stagger
                                     // puts the 4 q-addresses of each b128
                                     // read on disjoint banks (broadcast x16)
    __shared__ float g_lds[256];

    for (int s = 0; s < S; ++s) {
        float xp = Xp[s * G4 + r];   // independent of h: issue before the poll
        if (t < 256)
            h_lds[(t >> 6) * 68 + (t & 63)] = poll_h(&hs64[s * 256 + t], s);
        __syncthreads();

        float acc = 0.f;
        const float* hq = &h_lds[q * 68];
#pragma unroll
        for (int i4 = 0; i4 < 16; ++i4) {
            float4 hv = *(const float4*)&hq[4 * i4];
            acc += w[4 * i4] * hv.x + w[4 * i4 + 1] * hv.y +
                   w[4 * i4 + 2] * hv.z + w[4 * i4 + 3] * hv.w;
        }
        acc += __shfl_xor(acc, 1);
        acc += __shfl_xor(acc, 2);
        if (q == 0) {
            float gv = acc + xp;
            g_lds[rl] = (gt == 2) ? ftanh(gv) : fsigmoid(gv);
        }
        __syncthreads();
        if (t < 64) {
            float iv = g_lds[t], fv = g_lds[64 + t], gg = g_lds[128 + t], ov = g_lds[192 + t];
            c = fv * c + iv * gg;
            float h = ov * ftanh(c);
            publish_h(&hs64[(s + 1) * 256 + b * 64 + t], s + 1, h);
            hs[(s + 1) * HH + b * 64 + t] = h;   // plain copy for out_proj
        }
        __syncthreads();
    }
}

// ---------------------------------------------------------------------------
// Kernel D: logits = hs @ out_W.T + out_b; log_softmax per row.
// One wave per sentence row.
// ---------------------------------------------------------------------------
__global__ __launch_bounds__(256) void out_proj_kernel(
    const float* __restrict__ hs, const float* __restrict__ outW,
    const float* __restrict__ outb, float* __restrict__ out)
{
    const int row  = blockIdx.x * 4 + (threadIdx.x >> 6);
    const int lane = threadIdx.x & 63;
    const float* h = hs + HH + row * HH;   // skip zero row 0
    float logit = -1e30f;
    if (lane < TT) {
        const float* wr = outW + lane * HH;
        float a = outb[lane];
#pragma unroll 8
        for (int k = 0; k < HH; k += 4) {
            float4 hv = *(const float4*)&h[k];
            float4 wv = *(const float4*)&wr[k];
            a += hv.x * wv.x + hv.y * wv.y + hv.z * wv.z + hv.w * wv.w;
        }
        logit = a;
    }
    float mx = logit;
#pragma unroll
    for (int d = 32; d; d >>= 1) mx = fmaxf(mx, __shfl_xor(mx, d));
    float ex = (lane < TT) ? __expf(logit - mx) : 0.f;
    float sm = ex;
#pragma unroll
    for (int d = 32; d; d >>= 1) sm += __shfl_xor(sm, d);
    float ls = logit - mx - __logf(sm);
    if (lane < TT) out[row * TT + lane] = ls;
}

// ---------------------------------------------------------------------------
extern "C" void kernel_launch(void* const* d_in, const int* in_sizes, int n_in,
                              void* d_out, int out_size, void* d_ws, size_t ws_size,
                              hipStream_t stream)
{
    const int*   word_ids = (const int*)d_in[0];
    const int*   char_ids = (const int*)d_in[1];
    const int*   word_len = (const int*)d_in[2];
    const float* word_emb = (const float*)d_in[3];
    const float* char_emb = (const float*)d_in[4];
    const float* cWih     = (const float*)d_in[5];
    const float* cWhh     = (const float*)d_in[6];
    const float* cbih     = (const float*)d_in[7];
    const float* cbhh     = (const float*)d_in[8];
    const float* wWih     = (const float*)d_in[9];
    const float* wWhh     = (const float*)d_in[10];
    const float* wbih     = (const float*)d_in[11];
    const float* wbhh     = (const float*)d_in[12];
    const float* outW     = (const float*)d_in[13];
    const float* outb     = (const float*)d_in[14];
    float* out = (float*)d_out;

    // workspace layout (floats)
    float* h_char = (float*)d_ws;                  // 4096*64      = 262144
    float* Wt     = h_char + 262144;               // 192*1024     = 196608
    float* Xp     = Wt + 196608;                   // 4096*1024    = 4194304
    float* hs     = Xp + 4194304;                  // 4097*256     = 1048832
    u64*   hs64   = (u64*)(hs + 1048832);          // 4097*256 u64 (8B aligned)

    hipMemsetAsync(hs, 0, HH * sizeof(float), stream);          // h_0 = 0
    hipMemsetAsync(hs64, 0, 256 * sizeof(u64), stream);         // tag 0, h_0 = 0

    hipLaunchKernelGGL(char_lstm_kernel, dim3(S / CWPG), dim3(256), 0, stream,
                       char_ids, word_len, char_emb, cWih, cWhh, cbih, cbhh, h_char);
    hipLaunchKernelGGL(transpose_wih, dim3((KX * G4 + 255) / 256), dim3(256), 0, stream,
                       wWih, Wt);
    hipLaunchKernelGGL(xproj_kernel, dim3(S / SB), dim3(256), 0, stream,
                       word_ids, word_emb, h_char, Wt, wbih, wbhh, Xp);
    hipLaunchKernelGGL(word_lstm_kernel, dim3(4), dim3(1024), 0, stream,
                       Xp, wWhh, hs64, hs);
    hipLaunchKernelGGL(out_proj_kernel, dim3(S / 4), dim3(256), 0, stream,
                       hs, outW, outb, out);
}